// Round 10
// baseline (359.281 us; speedup 1.0000x reference)
//
#include <hip/hip_runtime.h>

#define NC 19
#define NB 10
#define NCELL (NC * NB)            // 190
#define NPART (3 * NCELL + 2 * NC) // 608: conf[190] pred[190] acc[190] psum[19] inval[19]
#define REP 4                      // conf/pred/acc replicas
#define REP16 16                   // psum replicas
#define NSLOT 32                   // global accumulator replicas
#define TPB 256
#define CHUNK 2048                 // pixels per block (8 per thread)
#define BLOCKS 1024                // 2^21 / 2048, exact

typedef float f32x4 __attribute__((ext_vector_type(4)));

// ---------------------------------------------------------------------------
// Pass 1: CLASS-OUTER sweeps. Each block owns a contiguous 2048-px chunk and
// reads the 19 planes SEQUENTIALLY (3 sweeps: max, sum, bin+histogram).
// At any instant each block maintains ONE contiguous stream -> the 20-way
// 8MiB-strided interleave (common to r1-r8, all stuck at ~412 cyc/VMEM-inst
// per CU) never occurs. Re-sweeps are L3-resident (167MB < 256MB).
// Class-outer also kills the psum[19] register tenant: per-class scalar ps
// flushed to LDS each c-iteration -> ~60 VGPR total, no allocator war.
// Bin-0 (~87% of entries) recovered in pass2 by subtraction:
//   pred(c,0) = valid(c) - sum_{b>=1} pred(c,b)
//   conf(c,0) = psum(c)  - sum_{b>=1} conf(c,b)
// ---------------------------------------------------------------------------
__global__ __launch_bounds__(TPB, 4) void cce_pass1(
    const float* __restrict__ logits, const int* __restrict__ tgt,
    float* __restrict__ gacc, int hw)
{
    constexpr int O_CONF = 0;
    constexpr int O_PRED = REP * NCELL;                 // 760
    constexpr int O_ACC  = 2 * REP * NCELL;             // 1520
    constexpr int O_PSUM = 3 * REP * NCELL;             // 2280
    constexpr int O_INV  = O_PSUM + REP16 * NC;         // 2584
    constexpr int LDS_N  = O_INV + NC;                  // 2603 floats = 10.4 KB

    __shared__ float hist[LDS_N];
    for (int i = threadIdx.x; i < LDS_N; i += TPB) hist[i] = 0.0f;
    __syncthreads();

    const int rep   = threadIdx.x & (REP - 1);
    const int rep16 = threadIdx.x & (REP16 - 1);
    const size_t px0 = (size_t)blockIdx.x * CHUNK + (size_t)threadIdx.x * 8;

    // targets for this thread's 8 pixels
    int tg[8];
    {
        const int4 t0 = *reinterpret_cast<const int4*>(tgt + px0);
        const int4 t1 = *reinterpret_cast<const int4*>(tgt + px0 + 4);
        tg[0]=t0.x; tg[1]=t0.y; tg[2]=t0.z; tg[3]=t0.w;
        tg[4]=t1.x; tg[5]=t1.y; tg[6]=t1.z; tg[7]=t1.w;
    }

    // ---- sweep 0: per-pixel max over classes (plane-sequential reads) ----
    float m[8];
#pragma unroll
    for (int j = 0; j < 8; ++j) m[j] = -1e30f;
#pragma unroll
    for (int c = 0; c < NC; ++c) {
        const float* pl = logits + (size_t)c * hw + px0;
        const f32x4 a = *reinterpret_cast<const f32x4*>(pl);
        const f32x4 b = *reinterpret_cast<const f32x4*>(pl + 4);
#pragma unroll
        for (int j = 0; j < 4; ++j) {
            m[j]     = fmaxf(m[j],     a[j]);
            m[4 + j] = fmaxf(m[4 + j], b[j]);
        }
    }

    // ---- sweep 1: per-pixel sum of exp(x - m) (L3-warm) ----
    float S[8];
#pragma unroll
    for (int j = 0; j < 8; ++j) S[j] = 0.0f;
#pragma unroll
    for (int c = 0; c < NC; ++c) {
        const float* pl = logits + (size_t)c * hw + px0;
        const f32x4 a = *reinterpret_cast<const f32x4*>(pl);
        const f32x4 b = *reinterpret_cast<const f32x4*>(pl + 4);
#pragma unroll
        for (int j = 0; j < 4; ++j) {
            S[j]     += __expf(a[j] - m[j]);
            S[4 + j] += __expf(b[j] - m[4 + j]);
        }
    }
    float rc[8];
#pragma unroll
    for (int j = 0; j < 8; ++j) rc[j] = __builtin_amdgcn_rcpf(S[j]);

    // ---- sweep 2: p, binning, histograms (L3-warm) ----
#pragma unroll
    for (int c = 0; c < NC; ++c) {
        const float* pl = logits + (size_t)c * hw + px0;
        const f32x4 a = *reinterpret_cast<const f32x4*>(pl);
        const f32x4 b = *reinterpret_cast<const f32x4*>(pl + 4);
        float x[8];
#pragma unroll
        for (int j = 0; j < 4; ++j) { x[j] = a[j]; x[4 + j] = b[j]; }

        float ps = 0.0f;
#pragma unroll
        for (int j = 0; j < 8; ++j) {
            const float p = __expf(x[j] - m[j]) * rc[j];
            ps += p;
            int bb = (int)ceilf(p * 10.0f) - 1;          // p<=0.1 -> bb<=0
            if (bb > 0) {                                // hot: bin >= 1 (~13%)
                bb = bb > NB - 1 ? NB - 1 : bb;
                atomicAdd(&hist[O_CONF + rep * NCELL + c * NB + bb], p);
                atomicAdd(&hist[O_PRED + rep * NCELL + c * NB + bb], 1.0f);
            }
            if (tg[j] == c && p > 0.0f) {                // correct-pixel count
                int bt = (int)ceilf(p * 10.0f) - 1;
                bt = bt < 0 ? 0 : (bt > NB - 1 ? NB - 1 : bt);
                atomicAdd(&hist[O_ACC + rep * NCELL + c * NB + bt], 1.0f);
            }
            if (!(p > 0.0f))                             // ultra-rare underflow
                atomicAdd(&hist[O_INV + c], 1.0f);
        }
        atomicAdd(&hist[O_PSUM + rep16 * NC + c], ps);   // per-class psum flush
    }
    __syncthreads();

    // Reduce replicas; flush block partials to one of NSLOT global slot sets.
    float* slot = gacc + (size_t)(blockIdx.x & (NSLOT - 1)) * NPART;
    for (int j = threadIdx.x; j < NPART; j += TPB) {
        float v = 0.0f;
        if (j < NCELL) {
            for (int rr = 0; rr < REP; ++rr) v += hist[O_CONF + rr * NCELL + j];
        } else if (j < 2 * NCELL) {
            for (int rr = 0; rr < REP; ++rr) v += hist[O_PRED + rr * NCELL + (j - NCELL)];
        } else if (j < 3 * NCELL) {
            for (int rr = 0; rr < REP; ++rr) v += hist[O_ACC + rr * NCELL + (j - 2 * NCELL)];
        } else if (j < 3 * NCELL + NC) {
            for (int rr = 0; rr < REP16; ++rr) v += hist[O_PSUM + rr * NC + (j - 3 * NCELL)];
        } else {
            v = hist[O_INV + (j - 3 * NCELL - NC)];
        }
        atomicAdd(&slot[j], v);
    }
}

// ---------------------------------------------------------------------------
// Pass 2: sum NSLOT slots, bin-0 corrections, 190-cell loss (double).
// slot layout: [0,190) conf, [190,380) pred, [380,570) acc, [570,589) psum,
//              [589,608) inval.
// ---------------------------------------------------------------------------
__global__ void cce_pass2(const float* __restrict__ gacc, float* __restrict__ out, int hw)
{
    __shared__ double fin[NPART];
    const int j = threadIdx.x; // blockDim = 640
    if (j < NPART) {
        double v = 0.0;
        for (int s = 0; s < NSLOT; ++s) v += (double)gacc[(size_t)s * NPART + j];
        fin[j] = v;
    }
    __syncthreads();

    if (j < NC) {
        double spred = 0.0, sconf = 0.0;
        for (int b = 1; b < NB; ++b) {
            spred += fin[NCELL + j * NB + b];
            sconf += fin[j * NB + b];
        }
        const double validc = (double)hw - fin[3 * NCELL + NC + j];
        fin[NCELL + j * NB] = validc - spred;             // pred(c,0)
        fin[j * NB]         = fin[3 * NCELL + j] - sconf; // conf(c,0)
    }
    __syncthreads();

    if (j < 64) {
        double tot = 0.0;
        for (int c = j; c < NCELL; c += 64) tot += fin[NCELL + c];
#pragma unroll
        for (int o = 32; o > 0; o >>= 1) tot += __shfl_down(tot, o);
        tot = __shfl(tot, 0);

        double loss = 0.0;
        for (int c = j; c < NCELL; c += 64) {
            const double pred = fin[NCELL + c];
            const double conf = fin[c];
            const double acc  = fin[2 * NCELL + c];
            const double d    = (acc - conf) / (pred + 1e-13);
            loss += d * d * (pred / tot);
        }
#pragma unroll
        for (int o = 32; o > 0; o >>= 1) loss += __shfl_down(loss, o);
        if (j == 0) out[0] = (float)loss;
    }
}

extern "C" void kernel_launch(void* const* d_in, const int* in_sizes, int n_in,
                              void* d_out, int out_size, void* d_ws, size_t ws_size,
                              hipStream_t stream)
{
    const float* logits = (const float*)d_in[0];
    const int*   tgt    = (const int*)d_in[1];
    float*       gacc   = (float*)d_ws;
    const int    hw     = in_sizes[1]; // 1024*2048

    hipMemsetAsync(gacc, 0, (size_t)NSLOT * NPART * sizeof(float), stream);
    cce_pass1<<<BLOCKS, TPB, 0, stream>>>(logits, tgt, gacc, hw);
    cce_pass2<<<1, 640, 0, stream>>>(gacc, (float*)d_out, hw);
}